// Round 1
// baseline (134.752 us; speedup 1.0000x reference)
//
#include <hip/hip_runtime.h>

// WaveletFeatureAugmentation: out[row] = concat(x[row] (4096 f32),
//   Linear14x14(wavedec_db4_approx_9levels(x[row]))).
// One block per row; DWT cascade ping-pongs in LDS.

#define ROWS 16384          // 32*512
#define N0   4096
#define OUTW 4110           // 4096 + 14

__device__ __constant__ float c_dec_lo[8] = {
    -0.010597401784997278f,  0.032883011666982945f,
     0.030841381835986965f, -0.18703481171888114f,
    -0.02798376941698385f,   0.6308807679295904f,
     0.7148465705525415f,    0.23037781330885523f};

__global__ __launch_bounds__(256) void wavelet_aug_kernel(
    const float* __restrict__ x, const float* __restrict__ W,
    const float* __restrict__ b, float* __restrict__ out)
{
    __shared__ float bufA[4096];
    __shared__ float bufB[2051];

    const int row = blockIdx.x;
    const int tid = threadIdx.x;
    const float* xr  = x   + (size_t)row * N0;
    float*       outr = out + (size_t)row * OUTW;

    // Load row into LDS and pass through to output. out row base is 8B-aligned
    // (4110*4 = 16440 bytes, multiple of 8) -> float2 stores are legal.
    for (int i = tid; i < N0 / 2; i += 256) {
        float2 v = reinterpret_cast<const float2*>(xr)[i];
        reinterpret_cast<float2*>(outr)[i] = v;
        bufA[2 * i]     = v.x;
        bufA[2 * i + 1] = v.y;
    }
    __syncthreads();

    // 9 DWT-lo levels, pywt 'symmetric' mode:
    //   y[i] = sum_k ext(2i+1-k) * dec_lo[k],  k in [0,8)
    //   ext(t) = a[-1-t] if t<0 ; a[2n-1-t] if t>=n ; a[t] otherwise
    const int nin_tab[9] = {4096, 2051, 1029, 518, 262, 134, 70, 38, 22};
    float* bin  = bufA;
    float* bout = bufB;
    #pragma unroll
    for (int lev = 0; lev < 9; ++lev) {
        const int n    = nin_tab[lev];
        const int nout = (n + 7) >> 1;
        for (int i = tid; i < nout; i += 256) {
            float acc = 0.f;
            #pragma unroll
            for (int k = 0; k < 8; ++k) {
                int t = 2 * i + 1 - k;
                int idx = (t < 0) ? (-1 - t) : ((t >= n) ? (2 * n - 1 - t) : t);
                acc += bin[idx] * c_dec_lo[k];
            }
            bout[i] = acc;
        }
        __syncthreads();
        float* tmp = bin; bin = bout; bout = tmp;
    }
    // After 9 levels the 14 approx coefficients live in `bin` (bufB).

    // aug[o] = b[o] + sum_f approx[f] * W[o][f]   (einsum 'bsf,of->bso')
    if (tid < 14) {
        float acc = b[tid];
        #pragma unroll
        for (int f = 0; f < 14; ++f)
            acc += bin[f] * W[tid * 14 + f];
        outr[N0 + tid] = acc;
    }
}

extern "C" void kernel_launch(void* const* d_in, const int* in_sizes, int n_in,
                              void* d_out, int out_size, void* d_ws, size_t ws_size,
                              hipStream_t stream) {
    const float* x = (const float*)d_in[0];   // [32,512,4096]
    const float* W = (const float*)d_in[1];   // [14,14]
    const float* b = (const float*)d_in[2];   // [14]
    float* out = (float*)d_out;               // [32,512,4110]
    wavelet_aug_kernel<<<ROWS, 256, 0, stream>>>(x, W, b, out);
}